// Round 1
// baseline (142.981 us; speedup 1.0000x reference)
//
#include <hip/hip_runtime.h>

// out[b, i, p] = (i == i2[p] || i == j2[p]) ? NRF[b,p] * 0.5f : 0.0f
// B=1024, N_ATOMS=64, NC2=2016. Pair p = i2*(i2-1)/2 + j2 (j2 < i2),
// i.e. np.tril_indices(64, k=-1) row-major order.
//
// Layout: NC2 = 2016 = 504 float4. Each thread owns one (i, p4) column
// and loops over a 64-batch slice -> pair decode amortized 64x.
// Total threads = 16 slices * 64 i * 504 p4 = 516096 = 2016 blocks * 256.

__device__ __forceinline__ int pair_row(int p) {
    // largest i with i*(i-1)/2 <= p  (i.e. the i2 of tril pair p)
    float f = sqrtf(8.0f * (float)p + 1.0f);
    int i = (int)((1.0f + f) * 0.5f);
    while (i * (i - 1) / 2 > p) --i;          // guard fp rounding
    while ((i + 1) * i / 2 <= p) ++i;
    return i;
}

__global__ __launch_bounds__(256) void transform_nrf_kernel(
    const float* __restrict__ nrf, float* __restrict__ out) {
    const int t     = blockIdx.x * 256 + threadIdx.x;
    const int pos   = t % 32256;   // 64 * 504
    const int slice = t / 32256;   // 0..15
    const int i     = pos / 504;
    const int p4    = pos % 504;
    const int p0    = p4 * 4;

    // Decode the 4 pairs this thread covers; membership is b-invariant.
    bool m[4];
#pragma unroll
    for (int k = 0; k < 4; ++k) {
        const int p  = p0 + k;
        const int r  = pair_row(p);
        const int j  = p - r * (r - 1) / 2;
        m[k] = (i == r) || (i == j);
    }

    const float4* __restrict__ nrf4 = (const float4*)nrf;
    float4* __restrict__ out4       = (float4*)out;

    const int bbase = slice * 64;
#pragma unroll 4
    for (int k = 0; k < 64; ++k) {
        const int b = bbase + k;
        const float4 v = nrf4[b * 504 + p4];
        float4 o;
        o.x = m[0] ? v.x * 0.5f : 0.0f;
        o.y = m[1] ? v.y * 0.5f : 0.0f;
        o.z = m[2] ? v.z * 0.5f : 0.0f;
        o.w = m[3] ? v.w * 0.5f : 0.0f;
        out4[(b * 64 + i) * 504 + p4] = o;
    }
}

extern "C" void kernel_launch(void* const* d_in, const int* in_sizes, int n_in,
                              void* d_out, int out_size, void* d_ws, size_t ws_size,
                              hipStream_t stream) {
    const float* nrf = (const float*)d_in[0];
    float* out       = (float*)d_out;
    // 2016 blocks * 256 threads, 64 batch-iterations per thread covers
    // 1024*64*2016 floats exactly.
    transform_nrf_kernel<<<2016, 256, 0, stream>>>(nrf, out);
}

// Round 3
// 98.606 us; speedup vs baseline: 1.4500x; 1.4500x over previous
//
#include <hip/hip_runtime.h>

// out[b, i, p] = (i == i2[p] || i == j2[p]) ? NRF[b,p] * 0.5f : 0.0f
// B=1024, N_ATOMS=64, NC2=2016. Pair p = i2*(i2-1)/2 + j2 (j2 < i2).
//
// Thread owns one (i, p4) column, loops over a 64-batch slice -> pair
// decode amortized 64x. Writes are a pure 528 MB stream: nontemporal
// stores keep the stream out of L2 (input stays cached; only ~128 KB
// of input is live at any instant).

typedef float f32x4 __attribute__((ext_vector_type(4)));

__device__ __forceinline__ int pair_row(int p) {
    float f = sqrtf(8.0f * (float)p + 1.0f);
    int i = (int)((1.0f + f) * 0.5f);
    while (i * (i - 1) / 2 > p) --i;
    while ((i + 1) * i / 2 <= p) ++i;
    return i;
}

__global__ __launch_bounds__(256) void transform_nrf_kernel(
    const float* __restrict__ nrf, float* __restrict__ out) {
    const int t     = blockIdx.x * 256 + threadIdx.x;
    const int pos   = t % 32256;   // 64 * 504
    const int slice = t / 32256;   // 0..15
    const int i     = pos / 504;
    const int p4    = pos % 504;
    const int p0    = p4 * 4;

    bool m[4];
#pragma unroll
    for (int k = 0; k < 4; ++k) {
        const int p  = p0 + k;
        const int r  = pair_row(p);
        const int j  = p - r * (r - 1) / 2;
        m[k] = (i == r) || (i == j);
    }

    const f32x4* __restrict__ nrf4 = (const f32x4*)nrf;
    f32x4* __restrict__ out4       = (f32x4*)out;

    const int bbase = slice * 64;
#pragma unroll 8
    for (int k = 0; k < 64; ++k) {
        const int b = bbase + k;
        const f32x4 v = nrf4[b * 504 + p4];
        f32x4 o;
        o.x = m[0] ? v.x * 0.5f : 0.0f;
        o.y = m[1] ? v.y * 0.5f : 0.0f;
        o.z = m[2] ? v.z * 0.5f : 0.0f;
        o.w = m[3] ? v.w * 0.5f : 0.0f;
        __builtin_nontemporal_store(o, &out4[(size_t)(b * 64 + i) * 504 + p4]);
    }
}

extern "C" void kernel_launch(void* const* d_in, const int* in_sizes, int n_in,
                              void* d_out, int out_size, void* d_ws, size_t ws_size,
                              hipStream_t stream) {
    const float* nrf = (const float*)d_in[0];
    float* out       = (float*)d_out;
    transform_nrf_kernel<<<2016, 256, 0, stream>>>(nrf, out);
}